// Round 5
// baseline (248.440 us; speedup 1.0000x reference)
//
#include <hip/hip_runtime.h>

// GCNConv(100k nodes, 1M edges, D=128) + two heads (128->64), fp32 in/out.
// R13: wave-uniform gather.
//  - k_gf gather: ONE node per wave step, 64-lane rows (half2/lane); all
//    loop bounds wave-uniform (no divergence); neighbor indices via
//    v_readlane (scalar base addressing); 8 row loads in flight per round;
//    edge tails via SGPR float masks folded into v_fma_mix; csr batch for
//    node i+1 prefetched while node i accumulates; off2 pairs for the
//    wave's 16 nodes preloaded in one coalesced load; dv recomputed as
//    rsqrt(deg+1) (dinv array gone).
//  - Pipeline 4 -> 3 kernels + memset: prep merged into k_scatter blocks
//    0..16; cursor zeroed by hipMemsetAsync; ebuf packed to 4B/edge
//    (s | (d&127)<<20), halving scatter write + node sort read.
// Pipeline: memset(cursor) -> scatter(+Wf/bias prep) -> node(sort+convert)
//           -> gf(gather rowsum + MFMA GEMM).

#define BLOCK 256
#define SB 512           // scatter blocks
#define NB_MAX 784       // max coarse buckets (n<=100352)
#define SLOT 2048        // per-bucket ebuf/csr capacity (avg 1280, max ~1500)

typedef _Float16 half8 __attribute__((ext_vector_type(8)));
typedef _Float16 half4 __attribute__((ext_vector_type(4)));
typedef _Float16 half2v __attribute__((ext_vector_type(2)));
typedef float f32x4 __attribute__((ext_vector_type(4)));

// ---------------- scatter (+ fused prep): Wf | bias | bucket scatter ----------------

__global__ __launch_bounds__(BLOCK) void k_scatter(
    const int* __restrict__ src, const int* __restrict__ dst, int E,
    const float* __restrict__ Wg, const float* __restrict__ Wh,
    const float* __restrict__ Wl, const float* __restrict__ bg,
    const float* __restrict__ bh, const float* __restrict__ bl,
    _Float16* __restrict__ WfT, float* __restrict__ bf,
    int* __restrict__ cursor, int* __restrict__ ebuf, int NB) {
    int b = blockIdx.x;
    if (b < 16) {  // Wf = Wg @ [Wh|Wl], stored transposed as fp16: WfT[c][k]
        int r = b * 8 + (threadIdx.x >> 5);
        int c0 = (threadIdx.x & 31) * 4;
        float a0 = 0.f, a1 = 0.f, a2 = 0.f, a3 = 0.f;
        for (int j = 0; j < 128; j++) {
            float wg = Wg[r * 128 + j];
            float4 wc;
            if (c0 < 64) wc = *(const float4*)(Wh + j * 64 + c0);
            else         wc = *(const float4*)(Wl + j * 64 + (c0 - 64));
            a0 += wg * wc.x; a1 += wg * wc.y; a2 += wg * wc.z; a3 += wg * wc.w;
        }
        WfT[(size_t)(c0 + 0) * 128 + r] = (_Float16)a0;
        WfT[(size_t)(c0 + 1) * 128 + r] = (_Float16)a1;
        WfT[(size_t)(c0 + 2) * 128 + r] = (_Float16)a2;
        WfT[(size_t)(c0 + 3) * 128 + r] = (_Float16)a3;
    } else if (b == 16) {  // bias fusion
        int c = threadIdx.x;
        if (c < 128) {
            float acc = (c < 64) ? bh[c] : bl[c - 64];
            for (int j = 0; j < 128; j++) {
                float wc = (c < 64) ? Wh[j * 64 + c] : Wl[j * 64 + (c - 64)];
                acc += bg[j] * wc;
            }
            bf[c] = acc;
        }
    } else {  // bucket scatter: LDS hist -> atomic range reserve -> scatter
        __shared__ int hist[NB_MAX];
        __shared__ int cur[NB_MAX];
        int blk = b - 17;
        int chunk = (E + SB - 1) / SB;
        int e0 = blk * chunk, e1 = min(E, e0 + chunk);
        for (int i = threadIdx.x; i < NB; i += BLOCK) hist[i] = 0;
        __syncthreads();
        for (int e = e0 + threadIdx.x; e < e1; e += BLOCK)
            atomicAdd(&hist[dst[e] >> 7], 1);
        __syncthreads();
        for (int i = threadIdx.x; i < NB; i += BLOCK) {
            int h = hist[i];
            cur[i] = i * SLOT + (h ? atomicAdd(&cursor[i], h) : 0);
        }
        __syncthreads();
        for (int e = e0 + threadIdx.x; e < e1; e += BLOCK) {
            int d = dst[e], s = src[e];
            int pos = atomicAdd(&cur[d >> 7], 1);      // LDS cursor
            ebuf[pos] = s | ((d & 127) << 20);         // packed 4B/edge
        }
    }
}

// ---------------- node: sort -> csr + off2, AND scale-convert own rows ----------------

__global__ __launch_bounds__(BLOCK) void k_node(const int* __restrict__ ebuf,
                                                const int* __restrict__ cursor,
                                                const float* __restrict__ x,
                                                int2* __restrict__ off2,
                                                int* __restrict__ csr,
                                                _Float16* __restrict__ xh,
                                                int n) {
    __shared__ int cnt[128];
    __shared__ int pre[128];
    __shared__ int cur[128];
    int bkt = blockIdx.x;
    int t = threadIdx.x;
    int node0 = bkt << 7;
    int nn = min(128, n - node0);
    int eb0 = bkt * SLOT;
    int eb1 = eb0 + cursor[bkt];                    // count after scatter

    if (t < 128) cnt[t] = 0;
    __syncthreads();
    for (int e = eb0 + t; e < eb1; e += BLOCK)
        atomicAdd(&cnt[(ebuf[e] >> 20) & 127], 1);
    __syncthreads();
    if (t < 128) pre[t] = cnt[t];
    __syncthreads();
    for (int ofs = 1; ofs < 128; ofs <<= 1) {
        int v = (t < 128 && t >= ofs) ? pre[t - ofs] : 0;
        __syncthreads();
        if (t < 128) pre[t] += v;
        __syncthreads();
    }
    if (t < 128) cur[t] = pre[t] - cnt[t];          // exclusive
    __syncthreads();
    if (t < nn)
        off2[node0 + t] = make_int2(eb0 + cur[t], eb0 + pre[t]);
    for (int e = eb0 + t; e < eb1; e += BLOCK) {
        int p = ebuf[e];
        int pos = atomicAdd(&cur[(p >> 20) & 127], 1);  // LDS atomic
        csr[eb0 + pos] = p & 0xFFFFF;
    }
    // scale-convert own rows: xh[i] = fp16(dinv_i * x[i])  (cnt[] stable)
    const float4* xr = (const float4*)(x + (size_t)node0 * 128);
    half4* xw = (half4*)(xh + (size_t)node0 * 128);
    for (int idx = t; idx < nn * 32; idx += BLOCK) {
        int row = idx >> 5;
        float dvL = rsqrtf((float)(cnt[row] + 1));
        float4 v = xr[idx];
        half4 o;
        o.x = (_Float16)(dvL * v.x); o.y = (_Float16)(dvL * v.y);
        o.z = (_Float16)(dvL * v.z); o.w = (_Float16)(dvL * v.w);
        xw[idx] = o;
    }
}

// ---------------- fused gather (wave-uniform) + MFMA final GEMM ----------------
// Block = 256 thr = 4 waves, tile = 64 nodes; wave w owns rows w*16..w*16+16.
// Per node (uniform across the wave): 64-lane row reads (half2/lane), csr
// batch prefetched one node ahead, neighbor index via readlane (scalar base),
// rounds of 8 rows with SGPR float masks (no divergence anywhere).
// Row -> XOR-swizzled LDS (16B chunks, chunk ^ (r&7)); wave-local, no barrier.
// GEMM: A-frags from LDS, B-frags 16B contiguous from fp16 WfT (L2-resident).

__global__ __launch_bounds__(BLOCK) void k_gf(const int2* __restrict__ off2,
                                              const int* __restrict__ csr,
                                              const _Float16* __restrict__ xh,
                                              const _Float16* __restrict__ WfT,
                                              const float* __restrict__ bf,
                                              float* __restrict__ out, int n) {
    __shared__ _Float16 lds[64 * 128];              // 16KB tile
    int wave = threadIdx.x >> 6;
    int lane = threadIdx.x & 63;
    int T0 = blockIdx.x * 64;
    int wrow0 = wave * 16;
    int nbase = T0 + wrow0;

    // preload off2 pairs for the wave's 16 nodes (one coalesced load)
    int pidx = min(nbase + (lane & 15), n - 1);
    int2 oe = off2[pidx];

    // prologue: csr batch for node 0
    int sb_cur;
    {
        int beg0 = __builtin_amdgcn_readlane(oe.x, 0);
        sb_cur = csr[beg0 + lane];                  // safe: within slot capacity
    }

    for (int i = 0; i < 16; i++) {
        // prefetch csr batch for next node (dup harmless at i=15)
        int inext = (i + 1) & 15;
        int begn = __builtin_amdgcn_readlane(oe.x, inext);
        int sb_next = csr[begn + lane];

        int beg = __builtin_amdgcn_readlane(oe.x, i);
        int end = __builtin_amdgcn_readlane(oe.y, i);
        int deg = end - beg;
        float dv = rsqrtf((float)(deg + 1));

        int r = wrow0 + i;
        int d = min(T0 + r, n - 1);
        half2v sv = ((const half2v*)(xh + (size_t)d * 128))[lane];  // self (scaled)
        float ax = (float)sv.x, ay = (float)sv.y;

        int b0 = 0;
        do {                                        // almost always one iter
            int sb = (b0 == 0) ? sb_cur : csr[beg + b0 + lane];
            int nb = min(64, deg - b0);
            for (int rb = 0; rb < nb; rb += 8) {
                half2v v[8];
                float m[8];
#pragma unroll
                for (int j = 0; j < 8; j++) {
                    int se = __builtin_amdgcn_readlane(sb, rb + j);
                    se = min(max(se, 0), n - 1);    // garbage-safe (masked below)
                    v[j] = ((const half2v*)(xh + (size_t)se * 128))[lane];
                    m[j] = (rb + j < nb) ? 1.f : 0.f;
                }
#pragma unroll
                for (int j = 0; j < 8; j++) {       // v_fma_mix: mask*val folded
                    ax += m[j] * (float)v[j].x;
                    ay += m[j] * (float)v[j].y;
                }
            }
            b0 += 64;
        } while (b0 < deg);
        sb_cur = sb_next;

        half2v o;
        o.x = (_Float16)(dv * ax);
        o.y = (_Float16)(dv * ay);
        int c = lane >> 2;                          // 16B chunk 0..15
        int off_h = (((c ^ (r & 7)) << 3) + ((lane & 3) << 1));
        *(half2v*)(lds + r * 128 + off_h) = o;      // 2-way bank alias (free)
    }

    // ---- GEMM phase (wave-local rows; compiler inserts lgkmcnt wait) ----
    int l15 = lane & 15, lk = lane >> 4;
    half8 a[4];
    {
        int r = wrow0 + l15;
#pragma unroll
        for (int kk = 0; kk < 4; kk++) {
            int ch = (kk * 4 + lk) ^ (l15 & 7);
            a[kk] = *(const half8*)(lds + (size_t)r * 128 + ch * 8);
        }
    }
    f32x4 acc[8];
#pragma unroll
    for (int cf = 0; cf < 8; cf++) acc[cf] = (f32x4){0.f, 0.f, 0.f, 0.f};
#pragma unroll
    for (int kk = 0; kk < 4; kk++) {
#pragma unroll
        for (int cf = 0; cf < 8; cf++) {
            half8 bfr = *(const half8*)(WfT + (size_t)(cf * 16 + l15) * 128 + kk * 32 + lk * 8);
            acc[cf] = __builtin_amdgcn_mfma_f32_16x16x32_f16(a[kk], bfr, acc[cf], 0, 0, 0);
        }
    }
#pragma unroll
    for (int cf = 0; cf < 8; cf++) {
        int c = cf * 16 + l15;
        float bv = bf[c];
        size_t cbase = (c < 64) ? (size_t)c : (size_t)n * 64 + (size_t)(c - 64);
        int r0 = T0 + wrow0 + lk * 4;
#pragma unroll
        for (int j = 0; j < 4; j++) {
            int rr = r0 + j;
            if (rr < n) out[cbase + (size_t)rr * 64] = acc[cf][j] + bv;
        }
    }
}

extern "C" void kernel_launch(void* const* d_in, const int* in_sizes, int n_in,
                              void* d_out, int out_size, void* d_ws, size_t ws_size,
                              hipStream_t stream) {
    const float* x  = (const float*)d_in[0];
    const int*   ei = (const int*)d_in[1];
    const float* Wg = (const float*)d_in[2];
    const float* bg = (const float*)d_in[3];
    const float* Wh = (const float*)d_in[4];
    const float* bh = (const float*)d_in[5];
    const float* Wl = (const float*)d_in[6];
    const float* bl = (const float*)d_in[7];
    float* out = (float*)d_out;

    int n = in_sizes[0] / 128;
    int E = in_sizes[1] / 2;
    const int* src = ei;
    const int* dst = ei + E;
    int NB = (n + 127) >> 7;

#define WS_TAKE(ptr, type, count)                                        \
    ptr = (type*)wsp;                                                    \
    wsp = (char*)(((size_t)(wsp + (size_t)(count) * sizeof(type)) + 255) \
                  & ~(size_t)255)

    char* wsp = (char*)d_ws;
    int*      cursor; WS_TAKE(cursor, int,      NB_MAX);
    int*      ebuf;   WS_TAKE(ebuf,   int,      (size_t)NB_MAX * SLOT);
    int2*     off2;   WS_TAKE(off2,   int2,     n);
    int*      csr;    WS_TAKE(csr,    int,      (size_t)NB_MAX * SLOT);
    _Float16* WfT;    WS_TAKE(WfT,    _Float16, 128 * 128);
    float*    bf;     WS_TAKE(bf,     float,    128);
    _Float16* xh;     WS_TAKE(xh,     _Float16, (size_t)n * 128);

    hipMemsetAsync(cursor, 0, (size_t)NB * 4, stream);
    k_scatter<<<17 + SB, BLOCK, 0, stream>>>(
        src, dst, E, Wg, Wh, Wl, bg, bh, bl, WfT, bf, cursor, ebuf, NB);
    k_node<<<NB, BLOCK, 0, stream>>>(ebuf, cursor, x, off2, csr, xh, n);
    k_gf<<<(n + 63) / 64, BLOCK, 0, stream>>>(off2, csr, xh, WfT, bf, out, n);
}